// Round 5
// baseline (375.976 us; speedup 1.0000x reference)
//
#include <hip/hip_runtime.h>
#include <stdint.h>

#define B_ 32
#define S_ 8192
#define H_ 256

#define SPB   128            // s-rows per attn block; grid.x = 64
#define NBLK  (S_ / SPB)     // 64
#define TROWS 16             // rows per DMA tile (16 KB)
#define NT    (SPB / TROWS)  // 8 tiles per block

// Raw barrier / waitcnt: avoid the compiler's vmcnt(0)-drain before s_barrier
// (the m97 ~20% stall). "memory" clobber pins ordering.
#define BARRIER()     asm volatile("s_barrier" ::: "memory")
#define WAIT_VM(n)    asm volatile("s_waitcnt vmcnt(" #n ")" ::: "memory")

// Async global->LDS DMA, 16 B/lane: one call = 64 lanes x 16 B = one
// contiguous 1 KB h_enc row -> contiguous 1 KB of LDS (base + lane*16).
__device__ __forceinline__ void async_row16(const float* gptr, float* lptr) {
    __builtin_amdgcn_global_load_lds(
        (const __attribute__((address_space(1))) void*)gptr,
        (__attribute__((address_space(3))) void*)lptr,
        16, 0, 0);
}

// All-lane sum within each 16-lane DPP row: 4 VALU rotate-adds, no LDS pipe.
__device__ __forceinline__ float row16_allsum(float x) {
    float t;
    t = __int_as_float(__builtin_amdgcn_update_dpp(0, __float_as_int(x), 0x121, 0xF, 0xF, false)); x += t; // ror:1
    t = __int_as_float(__builtin_amdgcn_update_dpp(0, __float_as_int(x), 0x122, 0xF, 0xF, false)); x += t; // ror:2
    t = __int_as_float(__builtin_amdgcn_update_dpp(0, __float_as_int(x), 0x124, 0xF, 0xF, false)); x += t; // ror:4
    t = __int_as_float(__builtin_amdgcn_update_dpp(0, __float_as_int(x), 0x128, 0xF, 0xF, false)); x += t; // ror:8
    return x;
}

// ---------------------------------------------------------------------------
// Kernel 1: v_part[ec][b][d] = sum_{e in chunk ec} h_d_t[b,e] * W[e,d]
// ---------------------------------------------------------------------------
__global__ __launch_bounds__(256) void gemv_hdtW(
    const float* __restrict__ hdt,
    const float* __restrict__ W,
    float* __restrict__ v_part)     // (8, B, H)
{
    const int b  = blockIdx.x;
    const int ec = blockIdx.y;
    const int d  = threadIdx.x;

    __shared__ float lh[32];
    if (d < 32) lh[d] = hdt[b * H_ + ec * 32 + d];
    __syncthreads();

    float acc = 0.f;
    const float* Wp = W + (size_t)(ec * 32) * H_ + d;
#pragma unroll
    for (int e = 0; e < 32; ++e) acc = fmaf(lh[e], Wp[(size_t)e * H_], acc);

    v_part[(size_t)(ec * B_ + b) * H_ + d] = acc;
}

// ---------------------------------------------------------------------------
// Kernel 2: single pass over h_enc via double-buffered global_load_lds DMA.
// Tile = 16 rows (16 KB). Pipeline: issue tile t+1, wait vmcnt(4) (own tile-t
// rows landed, tile t+1 stays in flight), raw barrier, compute from LDS,
// raw barrier. Compute keeps the 16-lane-group layout: group pid handles
// tile row pid (ds_read_b128 x4), DPP reduce, exp, ct FMAs.
// ---------------------------------------------------------------------------
__global__ __launch_bounds__(256) void attn_main(
    const float* __restrict__ v_part,   // (8, B, H)
    const float* __restrict__ h_enc,    // (B, S, H)
    const float* __restrict__ sum_exp,  // (B, S)
    const float* __restrict__ mask,     // (B, S)
    float* __restrict__ out_alphat,     // (B, S) unnormalized; finalize scales
    float* __restrict__ out_newsum,     // (B, S)
    float* __restrict__ part_den,       // (B, NBLK)
    float* __restrict__ part_ct)        // (B, NBLK, H)
{
    const int b    = blockIdx.y;
    const int bx   = blockIdx.x;
    const int tid  = threadIdx.x;
    const int lane = tid & 63;
    const int wave = tid >> 6;          // 0..3
    const int sub  = lane & 15;
    const int grp  = lane >> 4;
    const int pid  = wave * 4 + grp;    // 0..15
    const int s0   = bx * SPB;

    __shared__ __align__(16) float tile[2][TROWS * H_];  // 32 KiB
    __shared__ __align__(16) float lct[16][H_];          // 16 KiB
    __shared__ float lmult[SPB];
    __shared__ float lse[SPB];
    __shared__ float lalpha[SPB];
    __shared__ float lnew[SPB];
    __shared__ float lden[16];

    if (tid < SPB) {
        const float se = sum_exp[(size_t)b * S_ + s0 + tid];
        const float mk = mask[(size_t)b * S_ + s0 + tid];
        lse[tid]   = se;
        lmult[tid] = mk / se;
    }

    // v fragment: sum the 8 e-chunk partials (L2-hot). All loads consumed
    // here, so vmcnt is clean before the DMA pipeline starts.
    const float4* vp4 = reinterpret_cast<const float4*>(v_part);
    float4 vf0 = {0,0,0,0}, vf1 = {0,0,0,0}, vf2 = {0,0,0,0}, vf3 = {0,0,0,0};
#pragma unroll
    for (int ec = 0; ec < 8; ++ec) {
        const int base = (ec * B_ + b) * (H_ / 4);
        float4 p;
        p = vp4[base + 0*16 + sub]; vf0.x += p.x; vf0.y += p.y; vf0.z += p.z; vf0.w += p.w;
        p = vp4[base + 1*16 + sub]; vf1.x += p.x; vf1.y += p.y; vf1.z += p.z; vf1.w += p.w;
        p = vp4[base + 2*16 + sub]; vf2.x += p.x; vf2.y += p.y; vf2.z += p.z; vf2.w += p.w;
        p = vp4[base + 3*16 + sub]; vf3.x += p.x; vf3.y += p.y; vf3.z += p.z; vf3.w += p.w;
    }
    __syncthreads();   // lmult/lse visible; full drain OK here (pre-pipeline)

    const float* __restrict__ hb = h_enc + (size_t)(b * S_ + s0) * H_;

    // Prologue: DMA tile 0 (4 rows per wave; LDS dest wave-uniform).
#pragma unroll
    for (int k = 0; k < 4; ++k) {
        const int r = wave * 4 + k;
        async_row16(hb + (size_t)r * H_ + lane * 4, &tile[0][r * H_]);
    }

    float4 ct0 = {0,0,0,0}, ct1 = {0,0,0,0}, ct2 = {0,0,0,0}, ct3 = {0,0,0,0};
    float  den = 0.f;

#pragma unroll
    for (int t = 0; t < NT; ++t) {
        if (t < NT - 1) {   // issue next tile into the other buffer
            const int tb = (t + 1) & 1;
#pragma unroll
            for (int k = 0; k < 4; ++k) {
                const int r = wave * 4 + k;
                async_row16(hb + (size_t)((t + 1) * TROWS + r) * H_ + lane * 4,
                            &tile[tb][r * H_]);
            }
            WAIT_VM(4);     // tile t landed; tile t+1 still in flight
        } else {
            WAIT_VM(0);
        }
        BARRIER();          // all waves' tile-t rows visible

        const int ra = t * TROWS + pid;       // block-local row 0..127
        const float4* R = reinterpret_cast<const float4*>(&tile[t & 1][pid * H_]);
        const float4 a0 = R[0*16 + sub], a1 = R[1*16 + sub];
        const float4 a2 = R[2*16 + sub], a3 = R[3*16 + sub];

        float dot;
        dot = fmaf(vf0.x, a0.x, fmaf(vf0.y, a0.y, fmaf(vf0.z, a0.z, vf0.w * a0.w)));
        dot = fmaf(vf1.x, a1.x, fmaf(vf1.y, a1.y, fmaf(vf1.z, a1.z, fmaf(vf1.w, a1.w, dot))));
        dot = fmaf(vf2.x, a2.x, fmaf(vf2.y, a2.y, fmaf(vf2.z, a2.z, fmaf(vf2.w, a2.w, dot))));
        dot = fmaf(vf3.x, a3.x, fmaf(vf3.y, a3.y, fmaf(vf3.z, a3.z, fmaf(vf3.w, a3.w, dot))));
        dot = row16_allsum(dot);

        const float e   = __expf(dot);
        const float att = e * lmult[ra];
        if (sub == 0) {
            lalpha[ra] = att;
            lnew[ra]   = lse[ra] + e;
        }
        den += att;
        ct0.x = fmaf(att, a0.x, ct0.x); ct0.y = fmaf(att, a0.y, ct0.y);
        ct0.z = fmaf(att, a0.z, ct0.z); ct0.w = fmaf(att, a0.w, ct0.w);
        ct1.x = fmaf(att, a1.x, ct1.x); ct1.y = fmaf(att, a1.y, ct1.y);
        ct1.z = fmaf(att, a1.z, ct1.z); ct1.w = fmaf(att, a1.w, ct1.w);
        ct2.x = fmaf(att, a2.x, ct2.x); ct2.y = fmaf(att, a2.y, ct2.y);
        ct2.z = fmaf(att, a2.z, ct2.z); ct2.w = fmaf(att, a2.w, ct2.w);
        ct3.x = fmaf(att, a3.x, ct3.x); ct3.y = fmaf(att, a3.y, ct3.y);
        ct3.z = fmaf(att, a3.z, ct3.z); ct3.w = fmaf(att, a3.w, ct3.w);

        BARRIER();          // all waves done READING tile t before its buffer
    }                       // is re-targeted by DMA at iteration t+1

    // Block reduce: 16 per-group ct partials -> 256 columns, plain store.
    float4* dst = reinterpret_cast<float4*>(&lct[pid][0]);
    dst[0*16 + sub] = ct0;
    dst[1*16 + sub] = ct1;
    dst[2*16 + sub] = ct2;
    dst[3*16 + sub] = ct3;
    if (sub == 0) lden[pid] = den;
    __syncthreads();

    float tot = 0.f;
#pragma unroll
    for (int p = 0; p < 16; ++p) tot += lct[p][tid];
    part_ct[((size_t)b * NBLK + bx) * H_ + tid] = tot;

    if (tid == 0) {
        float d = 0.f;
#pragma unroll
        for (int p = 0; p < 16; ++p) d += lden[p];
        part_den[b * NBLK + bx] = d;
    }

    if (tid < SPB) {
        out_alphat[(size_t)b * S_ + s0 + tid] = lalpha[tid];
        out_newsum[(size_t)b * S_ + s0 + tid] = lnew[tid];
    }
}

// ---------------------------------------------------------------------------
// Kernel 3: grid (B, 17). sector 16 -> ct_e reduce+write; sectors 0..15 ->
// scale 512 alphat elements each.
// ---------------------------------------------------------------------------
__global__ __launch_bounds__(256) void finalize(
    const float* __restrict__ part_den,
    const float* __restrict__ part_ct,
    float* __restrict__ out_ct,
    float* __restrict__ out_alphat)
{
    const int b   = blockIdx.x;
    const int sec = blockIdx.y;
    const int tid = threadIdx.x;

    __shared__ float pd[NBLK];
    if (tid < NBLK) pd[tid] = part_den[b * NBLK + tid];
    __syncthreads();

    float den = 0.f;
#pragma unroll
    for (int k = 0; k < NBLK; ++k) den += pd[k];
    const float inv = 1.f / den;

    if (sec == 16) {
        float ct = 0.f;
        const float* pc = part_ct + (size_t)b * NBLK * H_ + tid;
#pragma unroll 8
        for (int k = 0; k < NBLK; ++k) ct += pc[(size_t)k * H_];
        out_ct[b * H_ + tid] = ct * inv;
    } else {
        float* oa = out_alphat + (size_t)b * S_ + sec * 512;
        oa[tid]       *= inv;
        oa[tid + 256] *= inv;
    }
}

extern "C" void kernel_launch(void* const* d_in, const int* in_sizes, int n_in,
                              void* d_out, int out_size, void* d_ws, size_t ws_size,
                              hipStream_t stream) {
    const float* h_d_t   = (const float*)d_in[0];
    const float* h_enc   = (const float*)d_in[1];
    const float* mask    = (const float*)d_in[2];
    const float* sum_exp = (const float*)d_in[3];
    const float* W       = (const float*)d_in[4];

    float* out        = (float*)d_out;
    float* out_ct     = out;
    float* out_alphat = out + B_ * H_;
    float* out_newsum = out + B_ * H_ + B_ * S_;

    float* ws       = (float*)d_ws;
    float* v_part   = ws;
    float* part_den = v_part + 8 * B_ * H_;
    float* part_ct  = part_den + B_ * NBLK;

    gemv_hdtW<<<dim3(B_, 8), 256, 0, stream>>>(h_d_t, W, v_part);
    attn_main<<<dim3(NBLK, B_), 256, 0, stream>>>(v_part, h_enc, sum_exp, mask,
                                                  out_alphat, out_newsum,
                                                  part_den, part_ct);
    finalize<<<dim3(B_, 17), 256, 0, stream>>>(part_den, part_ct, out_ct, out_alphat);
}

// Round 6
// 357.319 us; speedup vs baseline: 1.0522x; 1.0522x over previous
//
#include <hip/hip_runtime.h>

#define B_ 32
#define S_ 8192
#define H_ 256

#define SPB 128          // s-rows per attn block; grid.x = S_/SPB = 64
#define NBLK (S_ / SPB)  // 64 s-blocks per batch

typedef float f4v __attribute__((ext_vector_type(4)));

// Nontemporal float4 load: h_enc is streamed, minimal reuse.
__device__ __forceinline__ float4 ntld(const float4* p) {
    f4v v = __builtin_nontemporal_load(reinterpret_cast<const f4v*>(p));
    return make_float4(v.x, v.y, v.z, v.w);
}

// All-lane sum within each 16-lane DPP row: 4 VALU rotate-adds, no LDS pipe.
__device__ __forceinline__ float row16_allsum(float x) {
    float t;
    t = __int_as_float(__builtin_amdgcn_update_dpp(0, __float_as_int(x), 0x121, 0xF, 0xF, false)); x += t; // ror:1
    t = __int_as_float(__builtin_amdgcn_update_dpp(0, __float_as_int(x), 0x122, 0xF, 0xF, false)); x += t; // ror:2
    t = __int_as_float(__builtin_amdgcn_update_dpp(0, __float_as_int(x), 0x124, 0xF, 0xF, false)); x += t; // ror:4
    t = __int_as_float(__builtin_amdgcn_update_dpp(0, __float_as_int(x), 0x128, 0xF, 0xF, false)); x += t; // ror:8
    return x;
}

// ---------------------------------------------------------------------------
// Kernel 1: v_part[ec][b][d] = sum_{e in chunk ec} h_d_t[b,e] * W[e,d]
// ---------------------------------------------------------------------------
__global__ __launch_bounds__(256) void gemv_hdtW(
    const float* __restrict__ hdt,
    const float* __restrict__ W,
    float* __restrict__ v_part)     // (8, B, H)
{
    const int b  = blockIdx.x;
    const int ec = blockIdx.y;
    const int d  = threadIdx.x;

    __shared__ float lh[32];
    if (d < 32) lh[d] = hdt[b * H_ + ec * 32 + d];
    __syncthreads();

    float acc = 0.f;
    const float* Wp = W + (size_t)(ec * 32) * H_ + d;
#pragma unroll
    for (int e = 0; e < 32; ++e) acc = fmaf(lh[e], Wp[(size_t)e * H_], acc);

    v_part[(size_t)(ec * B_ + b) * H_ + d] = acc;
}

// ---------------------------------------------------------------------------
// Kernel 2: R4's exact streaming body, executed TWICE (diagnostic round).
// Pass 0 -> real outputs. Pass 1 -> dead ws scratch. Doubles duration so
// this dispatch surfaces in rocprof top-5 with full counters.
// ---------------------------------------------------------------------------
__global__ __launch_bounds__(256) void attn_main(
    const float* __restrict__ v_part,   // (8, B, H)
    const float* __restrict__ h_enc,    // (B, S, H)
    const float* __restrict__ sum_exp,  // (B, S)
    const float* __restrict__ mask,     // (B, S)
    float* __restrict__ out_alphat,     // (B, S) pass-0 real
    float* __restrict__ out_newsum,     // (B, S) pass-0 real
    float* __restrict__ part_den,       // (B, NBLK) pass-0 real
    float* __restrict__ part_ct,        // (B, NBLK, H) pass-0 real
    float* __restrict__ alt_alphat,     // scratch (pass 1)
    float* __restrict__ alt_newsum,     // scratch (pass 1)
    float* __restrict__ alt_den,        // scratch (pass 1)
    float* __restrict__ alt_ct)         // scratch (pass 1)
{
    const int b    = blockIdx.y;
    const int bx   = blockIdx.x;
    const int tid  = threadIdx.x;
    const int lane = tid & 63;
    const int wave = tid >> 6;          // 0..3
    const int sub  = lane & 15;
    const int grp  = lane >> 4;
    const int pid  = wave * 4 + grp;    // 0..15
    const int s0   = bx * SPB;

    __shared__ float lmult[SPB];
    __shared__ float lse[SPB];
    __shared__ float lalpha[SPB];
    __shared__ float lnew[SPB];
    __shared__ __align__(16) float lct[16][H_];   // 16 KiB
    __shared__ float lden[16];

    if (tid < SPB) {
        const float se = sum_exp[(size_t)b * S_ + s0 + tid];
        const float mk = mask[(size_t)b * S_ + s0 + tid];
        lse[tid]   = se;
        lmult[tid] = mk / se;
    }
    __syncthreads();

    // v fragment: sum the 8 e-chunk partials (L2-hot)
    const float4* vp4 = reinterpret_cast<const float4*>(v_part);
    float4 vf0 = {0,0,0,0}, vf1 = {0,0,0,0}, vf2 = {0,0,0,0}, vf3 = {0,0,0,0};
#pragma unroll
    for (int ec = 0; ec < 8; ++ec) {
        const int base = (ec * B_ + b) * (H_ / 4);
        float4 p;
        p = vp4[base + 0*16 + sub]; vf0.x += p.x; vf0.y += p.y; vf0.z += p.z; vf0.w += p.w;
        p = vp4[base + 1*16 + sub]; vf1.x += p.x; vf1.y += p.y; vf1.z += p.z; vf1.w += p.w;
        p = vp4[base + 2*16 + sub]; vf2.x += p.x; vf2.y += p.y; vf2.z += p.z; vf2.w += p.w;
        p = vp4[base + 3*16 + sub]; vf3.x += p.x; vf3.y += p.y; vf3.z += p.z; vf3.w += p.w;
    }

    const float* __restrict__ hb = h_enc + (size_t)b * S_ * H_;
    const float4* pa = reinterpret_cast<const float4*>(hb + (size_t)s0 * H_)
                       + (size_t)(pid * 2) * 64;

    for (int pass = 0; pass < 2; ++pass) {
        float* __restrict__ p_alphat = pass ? alt_alphat : out_alphat;
        float* __restrict__ p_newsum = pass ? alt_newsum : out_newsum;
        float* __restrict__ p_den    = pass ? alt_den    : part_den;
        float* __restrict__ p_ct     = pass ? alt_ct     : part_ct;

        float4 ct0 = {0,0,0,0}, ct1 = {0,0,0,0}, ct2 = {0,0,0,0}, ct3 = {0,0,0,0};
        float  den = 0.f;

        // Prologue: load iteration 0's rows.
        float4 a0 = ntld(pa + 0*16 + sub), a1 = ntld(pa + 1*16 + sub);
        float4 a2 = ntld(pa + 2*16 + sub), a3 = ntld(pa + 3*16 + sub);
        float4 b0 = ntld(pa + 64 + 0*16 + sub), b1 = ntld(pa + 64 + 1*16 + sub);
        float4 b2 = ntld(pa + 64 + 2*16 + sub), b3 = ntld(pa + 64 + 3*16 + sub);

#pragma unroll
        for (int i = 0; i < SPB / 32; ++i) {            // 4 iterations, 2 rows/group
            float4 na0, na1, na2, na3, nb0, nb1, nb2, nb3;
            if (i < SPB / 32 - 1) {                     // prefetch next iteration
                const float4* qa = pa + (size_t)(i + 1) * 32 * 64;
                na0 = ntld(qa + 0*16 + sub); na1 = ntld(qa + 1*16 + sub);
                na2 = ntld(qa + 2*16 + sub); na3 = ntld(qa + 3*16 + sub);
                nb0 = ntld(qa + 64 + 0*16 + sub); nb1 = ntld(qa + 64 + 1*16 + sub);
                nb2 = ntld(qa + 64 + 2*16 + sub); nb3 = ntld(qa + 64 + 3*16 + sub);
            }

            const int ra = i * 32 + pid * 2;
            const int rb = ra + 1;

            float da, db;
            da = fmaf(vf0.x, a0.x, fmaf(vf0.y, a0.y, fmaf(vf0.z, a0.z, vf0.w * a0.w)));
            da = fmaf(vf1.x, a1.x, fmaf(vf1.y, a1.y, fmaf(vf1.z, a1.z, fmaf(vf1.w, a1.w, da))));
            da = fmaf(vf2.x, a2.x, fmaf(vf2.y, a2.y, fmaf(vf2.z, a2.z, fmaf(vf2.w, a2.w, da))));
            da = fmaf(vf3.x, a3.x, fmaf(vf3.y, a3.y, fmaf(vf3.z, a3.z, fmaf(vf3.w, a3.w, da))));
            db = fmaf(vf0.x, b0.x, fmaf(vf0.y, b0.y, fmaf(vf0.z, b0.z, vf0.w * b0.w)));
            db = fmaf(vf1.x, b1.x, fmaf(vf1.y, b1.y, fmaf(vf1.z, b1.z, fmaf(vf1.w, b1.w, db))));
            db = fmaf(vf2.x, b2.x, fmaf(vf2.y, b2.y, fmaf(vf2.z, b2.z, fmaf(vf2.w, b2.w, db))));
            db = fmaf(vf3.x, b3.x, fmaf(vf3.y, b3.y, fmaf(vf3.z, b3.z, fmaf(vf3.w, b3.w, db))));

            da = row16_allsum(da);
            db = row16_allsum(db);

            const float ea = __expf(da);
            const float eb = __expf(db);
            const float atta = ea * lmult[ra];
            const float attb = eb * lmult[rb];
            if (sub == 0) {
                lalpha[ra] = atta;  lnew[ra] = lse[ra] + ea;
                lalpha[rb] = attb;  lnew[rb] = lse[rb] + eb;
            }
            den += atta + attb;
            ct0.x = fmaf(atta, a0.x, fmaf(attb, b0.x, ct0.x));
            ct0.y = fmaf(atta, a0.y, fmaf(attb, b0.y, ct0.y));
            ct0.z = fmaf(atta, a0.z, fmaf(attb, b0.z, ct0.z));
            ct0.w = fmaf(atta, a0.w, fmaf(attb, b0.w, ct0.w));
            ct1.x = fmaf(atta, a1.x, fmaf(attb, b1.x, ct1.x));
            ct1.y = fmaf(atta, a1.y, fmaf(attb, b1.y, ct1.y));
            ct1.z = fmaf(atta, a1.z, fmaf(attb, b1.z, ct1.z));
            ct1.w = fmaf(atta, a1.w, fmaf(attb, b1.w, ct1.w));
            ct2.x = fmaf(atta, a2.x, fmaf(attb, b2.x, ct2.x));
            ct2.y = fmaf(atta, a2.y, fmaf(attb, b2.y, ct2.y));
            ct2.z = fmaf(atta, a2.z, fmaf(attb, b2.z, ct2.z));
            ct2.w = fmaf(atta, a2.w, fmaf(attb, b2.w, ct2.w));
            ct3.x = fmaf(atta, a3.x, fmaf(attb, b3.x, ct3.x));
            ct3.y = fmaf(atta, a3.y, fmaf(attb, b3.y, ct3.y));
            ct3.z = fmaf(atta, a3.z, fmaf(attb, b3.z, ct3.z));
            ct3.w = fmaf(atta, a3.w, fmaf(attb, b3.w, ct3.w));

            if (i < SPB / 32 - 1) {
                a0 = na0; a1 = na1; a2 = na2; a3 = na3;
                b0 = nb0; b1 = nb1; b2 = nb2; b3 = nb3;
            }
        }

        // Block reduce: 16 per-group ct partials -> 256 columns, plain store.
        float4* dst = reinterpret_cast<float4*>(&lct[pid][0]);
        dst[0*16 + sub] = ct0;
        dst[1*16 + sub] = ct1;
        dst[2*16 + sub] = ct2;
        dst[3*16 + sub] = ct3;
        if (sub == 0) lden[pid] = den;
        __syncthreads();

        float tot = 0.f;
#pragma unroll
        for (int p = 0; p < 16; ++p) tot += lct[p][tid];
        p_ct[((size_t)b * NBLK + bx) * H_ + tid] = tot;

        if (tid == 0) {
            float d = 0.f;
#pragma unroll
            for (int p = 0; p < 16; ++p) d += lden[p];
            p_den[b * NBLK + bx] = d;
        }

        if (tid < SPB) {
            p_alphat[(size_t)b * S_ + s0 + tid] = lalpha[tid];
            p_newsum[(size_t)b * S_ + s0 + tid] = lnew[tid];
        }
        __syncthreads();   // lct/lalpha/lnew safe to reuse in pass 1
    }
}

// ---------------------------------------------------------------------------
// Kernel 3: grid (B, 17). sector 16 -> ct_e reduce+write; sectors 0..15 ->
// scale 512 alphat elements each.
// ---------------------------------------------------------------------------
__global__ __launch_bounds__(256) void finalize(
    const float* __restrict__ part_den,
    const float* __restrict__ part_ct,
    float* __restrict__ out_ct,
    float* __restrict__ out_alphat)
{
    const int b   = blockIdx.x;
    const int sec = blockIdx.y;
    const int tid = threadIdx.x;

    __shared__ float pd[NBLK];
    if (tid < NBLK) pd[tid] = part_den[b * NBLK + tid];
    __syncthreads();

    float den = 0.f;
#pragma unroll
    for (int k = 0; k < NBLK; ++k) den += pd[k];
    const float inv = 1.f / den;

    if (sec == 16) {
        float ct = 0.f;
        const float* pc = part_ct + (size_t)b * NBLK * H_ + tid;
#pragma unroll 8
        for (int k = 0; k < NBLK; ++k) ct += pc[(size_t)k * H_];
        out_ct[b * H_ + tid] = ct * inv;
    } else {
        float* oa = out_alphat + (size_t)b * S_ + sec * 512;
        oa[tid]       *= inv;
        oa[tid + 256] *= inv;
    }
}

extern "C" void kernel_launch(void* const* d_in, const int* in_sizes, int n_in,
                              void* d_out, int out_size, void* d_ws, size_t ws_size,
                              hipStream_t stream) {
    const float* h_d_t   = (const float*)d_in[0];
    const float* h_enc   = (const float*)d_in[1];
    const float* mask    = (const float*)d_in[2];
    const float* sum_exp = (const float*)d_in[3];
    const float* W       = (const float*)d_in[4];

    float* out        = (float*)d_out;
    float* out_ct     = out;
    float* out_alphat = out + B_ * H_;
    float* out_newsum = out + B_ * H_ + B_ * S_;

    // ws layout: [v_part][part_den][part_ct] + pass-1 scratch (dead writes)
    float* ws         = (float*)d_ws;
    float* v_part     = ws;                              // 8*B*H
    float* part_den   = v_part + 8 * B_ * H_;            // B*NBLK
    float* part_ct    = part_den + B_ * NBLK;            // B*NBLK*H
    float* alt_den    = part_ct + (size_t)B_ * NBLK * H_;
    float* alt_ct     = alt_den + B_ * NBLK;
    float* alt_alphat = alt_ct + (size_t)B_ * NBLK * H_;
    float* alt_newsum = alt_alphat + (size_t)B_ * S_;

    gemv_hdtW<<<dim3(B_, 8), 256, 0, stream>>>(h_d_t, W, v_part);
    attn_main<<<dim3(NBLK, B_), 256, 0, stream>>>(v_part, h_enc, sum_exp, mask,
                                                  out_alphat, out_newsum,
                                                  part_den, part_ct,
                                                  alt_alphat, alt_newsum,
                                                  alt_den, alt_ct);
    finalize<<<dim3(B_, 17), 256, 0, stream>>>(part_den, part_ct, out_ct, out_alphat);
}